// Round 1
// baseline (297.775 us; speedup 1.0000x reference)
//
#include <hip/hip_runtime.h>

// DynamicOversizeConv2d: per (b,c) pair [2048 total], 96x96 matrices:
//   M_h = softmax_rows(Q K^T) + band_h(c);  M_w = softmax_rows(Q^T K) + band_w(c)
//   Out = (M_h V) M_w^T
// Inputs fp32, output fp32, internal compute fp16 MFMA (absmax 0.031 vs 0.119).
//
// R6 pipeline restructure (latency-bound per rocprof: MfmaUtil 4.5%, VALU 18%,
// HBM 20%, all idle):
//  - Persistent grid of 512 blocks (exactly 2/CU), 4 pairs/block; c = pair&255
//    is block-invariant (512 % 256 == 0) so band kernels load once.
//  - Next pair's Q/K/V prefetched into registers right after current staging
//    consumes them; loads stay in flight across barriers.
//  - Raw s_barrier + explicit lgkmcnt(0) (NOT __syncthreads) so the compiler's
//    vmcnt(0) barrier drain never serializes prefetch loads / output stores.
//  - Output stored directly from acc (64B segment per quad, j-pairs cover full
//    128B lines -> L2 write-combine); fp32 ostage + 2 barriers removed.
// Barriers: 4 per pair (was 5). LDS = 4 f16 tiles (96x104) + 26 floats.

typedef unsigned short u16;
typedef unsigned int u32;
typedef __attribute__((ext_vector_type(8))) _Float16 half8;
typedef __attribute__((ext_vector_type(4))) float floatx4;

#define NN 96
#define LD 104            // f16-tile row pitch (elems): 208 B = 16B-aligned rows
#define NT 384
#define PAIRS 2048
#define GRID 512
#define ITERS (PAIRS / GRID)
#define IMG 9216
#define SMEM_BYTES (4 * NN * LD * 2 + 26 * 4)  // 79,976 -> 2 blocks/CU

__device__ __forceinline__ u16 f2h(float f) {
  union { _Float16 h; u16 u; } x;
  x.h = (_Float16)f;  // v_cvt_f16_f32 RNE
  return x.u;
}
__device__ __forceinline__ u32 pk(float lo, float hi) {
  return (u32)f2h(lo) | ((u32)f2h(hi) << 16);
}

// Workgroup barrier WITHOUT the __syncthreads vmcnt(0) drain: LDS ordering via
// explicit lgkmcnt(0); memory-clobber asm on both sides pins memory ops.
__device__ __forceinline__ void bar() {
  asm volatile("s_waitcnt lgkmcnt(0)" ::: "memory");
  __builtin_amdgcn_s_barrier();
  asm volatile("" ::: "memory");
}

// acc[j] (j=0..5) = row-stripe x all-cols: D[16w+quad*4+v][16j+ln].
// A row = arow (=16w+ln) of A-tile; BT rows 16j+ln. 3 k-steps of 32.
__device__ __forceinline__ void mm16(const u16* A, const u16* B, int arow,
                                     int ln, int quad, floatx4 acc[6]) {
#pragma unroll
  for (int j = 0; j < 6; ++j) acc[j] = (floatx4){0.f, 0.f, 0.f, 0.f};
#pragma unroll
  for (int ks = 0; ks < 3; ++ks) {
    const int kb = ks * 32 + quad * 8;
    const half8 a = *(const half8*)(A + arow * LD + kb);
    half8 b[6];
#pragma unroll
    for (int j = 0; j < 6; ++j)
      b[j] = *(const half8*)(B + (j * 16 + ln) * LD + kb);
#pragma unroll
    for (int j = 0; j < 6; ++j)
      acc[j] = __builtin_amdgcn_mfma_f32_16x16x32_f16(a, b[j], acc[j], 0, 0, 0);
  }
}

// Wave-local row softmax: row R = R0+quad*4+v lives in one quad across acc[0..5].
__device__ __forceinline__ void softmax_inplace(floatx4 acc[6]) {
#pragma unroll
  for (int v = 0; v < 4; ++v) {
    float m = acc[0][v];
#pragma unroll
    for (int j = 1; j < 6; ++j) m = fmaxf(m, acc[j][v]);
    m = fmaxf(m, __shfl_xor(m, 1));
    m = fmaxf(m, __shfl_xor(m, 2));
    m = fmaxf(m, __shfl_xor(m, 4));
    m = fmaxf(m, __shfl_xor(m, 8));
    float s = 0.f;
#pragma unroll
    for (int j = 0; j < 6; ++j) {
      const float e = __expf(acc[j][v] - m);
      acc[j][v] = e;
      s += e;
    }
    s += __shfl_xor(s, 1);
    s += __shfl_xor(s, 2);
    s += __shfl_xor(s, 4);
    s += __shfl_xor(s, 8);
    const float inv = __builtin_amdgcn_rcpf(s);
#pragma unroll
    for (int j = 0; j < 6; ++j) acc[j][v] *= inv;
  }
}

// Add band and store f16 stripe rows to D.
__device__ __forceinline__ void band_store(const floatx4 acc[6], int R0, int ln,
                                           int quad, const float* band13, u16* D) {
#pragma unroll
  for (int v = 0; v < 4; ++v) {
    const int R = R0 + quad * 4 + v;
#pragma unroll
    for (int j = 0; j < 6; ++j) {
      const int C = j * 16 + ln;
      const int off = C - R + 6;
      const float bnd = ((unsigned)off < 13u) ? band13[off] : 0.f;
      D[R * LD + C] = f2h(acc[j][v] + bnd);
    }
  }
}

extern "C" __global__ void __launch_bounds__(NT, 3)
doc_kernel(const float* __restrict__ qg, const float* __restrict__ kg,
           const float* __restrict__ vg, const float* __restrict__ khg,
           const float* __restrict__ kwg, float* __restrict__ og) {
  extern __shared__ char smem[];
  u16* b0 = (u16*)smem;       // Q   -> M_h
  u16* b1 = b0 + NN * LD;     // K   -> M_w
  u16* b2 = b1 + NN * LD;     // Q^T -> V^T
  u16* b3 = b2 + NN * LD;     // K^T -> V1
  float* kh13 = (float*)(b3 + NN * LD);
  float* kw13 = kh13 + 13;

  const int tid = threadIdx.x;
  const int lane = tid & 63;
  const int wv = tid >> 6;      // 0..5
  const int quad = lane >> 4;
  const int ln = lane & 15;
  const int R0 = wv * 16;       // owned row stripe
  const int arow = R0 + ln;
  const int c = blockIdx.x & 255;  // == pair & 255 for all pairs of this block

  // Load-mapping (1152 tasks = 3/thread of 2 rows x 4 cols):
  // m=t/192 (col super), rs=(t%192)/4 (row pair), g=t&3 (col sub). Wave = fixed
  // m, rs spans 16, g spans 4 -> 64B global lines; transposed LDS store bank =
  // (16(g&1)+rs)%32 -> 2-way (free).
  int r0_[3], c0_[3], src_[3];
#pragma unroll
  for (int it = 0; it < 3; ++it) {
    const int t = tid + it * NT;
    const int m = t / 192;
    const int rs = (t % 192) >> 2;
    const int g = t & 3;
    r0_[it] = rs * 2;
    c0_[it] = m * 16 + g * 4;
    src_[it] = r0_[it] * NN + c0_[it];
  }

  if (tid < 13)
    kh13[tid] = khg[c * 13 + tid];
  else if (tid < 26)
    kw13[tid - 13] = kwg[c * 13 + tid - 13];

  // Prologue: issue pair-0 loads.
  float4 pq[3][2], pkk[3][2], pv[3][2];
  {
    const float* q = qg + (size_t)blockIdx.x * IMG;
    const float* k = kg + (size_t)blockIdx.x * IMG;
    const float* v = vg + (size_t)blockIdx.x * IMG;
#pragma unroll
    for (int it = 0; it < 3; ++it) {
      pq[it][0] = *(const float4*)(q + src_[it]);
      pq[it][1] = *(const float4*)(q + src_[it] + NN);
      pkk[it][0] = *(const float4*)(k + src_[it]);
      pkk[it][1] = *(const float4*)(k + src_[it] + NN);
      pv[it][0] = *(const float4*)(v + src_[it]);
      pv[it][1] = *(const float4*)(v + src_[it] + NN);
    }
  }

  u32 vh[3][4];
  floatx4 acc[6];

  for (int itr = 0; itr < ITERS; ++itr) {
    const int pair = blockIdx.x + itr * GRID;
    float* o = og + (size_t)pair * IMG;

    if (itr) bar();  // prev iter's LDS readers done before re-staging (B0)

    // Stage current pair from regs into LDS; pack vh.
#pragma unroll
    for (int it = 0; it < 3; ++it) {
      const int r0 = r0_[it], c0 = c0_[it];
      const float4 qa = pq[it][0], qb = pq[it][1];
      const float4 ka = pkk[it][0], kb = pkk[it][1];
      const float4 va = pv[it][0], vb = pv[it][1];
      *(uint2*)(b0 + r0 * LD + c0) = make_uint2(pk(qa.x, qa.y), pk(qa.z, qa.w));
      *(uint2*)(b0 + (r0 + 1) * LD + c0) = make_uint2(pk(qb.x, qb.y), pk(qb.z, qb.w));
      *(uint2*)(b1 + r0 * LD + c0) = make_uint2(pk(ka.x, ka.y), pk(ka.z, ka.w));
      *(uint2*)(b1 + (r0 + 1) * LD + c0) = make_uint2(pk(kb.x, kb.y), pk(kb.z, kb.w));
      // transposed: T[col][r0] = f16(row r0) | f16(row r0+1)<<16
      *(u32*)(b2 + (c0 + 0) * LD + r0) = pk(qa.x, qb.x);
      *(u32*)(b2 + (c0 + 1) * LD + r0) = pk(qa.y, qb.y);
      *(u32*)(b2 + (c0 + 2) * LD + r0) = pk(qa.z, qb.z);
      *(u32*)(b2 + (c0 + 3) * LD + r0) = pk(qa.w, qb.w);
      *(u32*)(b3 + (c0 + 0) * LD + r0) = pk(ka.x, kb.x);
      *(u32*)(b3 + (c0 + 1) * LD + r0) = pk(ka.y, kb.y);
      *(u32*)(b3 + (c0 + 2) * LD + r0) = pk(ka.z, kb.z);
      *(u32*)(b3 + (c0 + 3) * LD + r0) = pk(ka.w, kb.w);
      vh[it][0] = pk(va.x, vb.x);
      vh[it][1] = pk(va.y, vb.y);
      vh[it][2] = pk(va.z, vb.z);
      vh[it][3] = pk(va.w, vb.w);
    }
    // Prefetch next pair's Q,K: regs just freed; loads fly under stages A-D.
    if (itr + 1 < ITERS) {
      const float* qn = qg + (size_t)(pair + GRID) * IMG;
      const float* kn = kg + (size_t)(pair + GRID) * IMG;
#pragma unroll
      for (int it = 0; it < 3; ++it) {
        pq[it][0] = *(const float4*)(qn + src_[it]);
        pq[it][1] = *(const float4*)(qn + src_[it] + NN);
        pkk[it][0] = *(const float4*)(kn + src_[it]);
        pkk[it][1] = *(const float4*)(kn + src_[it] + NN);
      }
    }
    bar();  // B1

    // Stage A: S_h stripe = Q(own rows) K^T -> wave-local softmax -> M_h into b0
    // (own stripe of b0 is read only by this wave in stage B -> no barrier).
    mm16(b0, b1, arow, ln, quad, acc);
    softmax_inplace(acc);
    band_store(acc, R0, ln, quad, kh13, b0);

    // Stage C: S_w stripe = Q^T(own rows) K; softmax now, store M_w after B2
    // (b1 still being read by slower waves' stage A; b2 gets V^T).
    mm16(b2, b3, arow, ln, quad, acc);
    softmax_inplace(acc);
    bar();  // B2
    band_store(acc, R0, ln, quad, kw13, b1);
#pragma unroll
    for (int it = 0; it < 3; ++it) {
      const int r0 = r0_[it], c0 = c0_[it];
#pragma unroll
      for (int j = 0; j < 4; ++j)
        *(u32*)(b2 + (c0 + j) * LD + r0) = vh[it][j];
    }
    // Prefetch next pair's V (vh already packed; pv free). Covered by stages B+D.
    if (itr + 1 < ITERS) {
      const float* vn = vg + (size_t)(pair + GRID) * IMG;
#pragma unroll
      for (int it = 0; it < 3; ++it) {
        pv[it][0] = *(const float4*)(vn + src_[it]);
        pv[it][1] = *(const float4*)(vn + src_[it] + NN);
      }
    }
    bar();  // B3

    // Stage B: V1 stripe = M_h(own) V (BT = V^T in b2); f16 to b3 own stripe
    // (self-read only in stage D -> no barrier).
    mm16(b0, b2, arow, ln, quad, acc);
#pragma unroll
    for (int v4 = 0; v4 < 4; ++v4) {
      const int R = R0 + quad * 4 + v4;
#pragma unroll
      for (int j = 0; j < 6; ++j)
        b3[R * LD + (j * 16 + ln)] = f2h(acc[j][v4]);
    }

    // Stage D: Out stripe = V1(own) M_w^T (BT = M_w in b1); store straight to
    // global: per (j,v4) each quad writes 64B contiguous; j-pairs complete
    // 128B lines -> write-combines. Stores drain under next iter's compute.
    mm16(b3, b1, arow, ln, quad, acc);
#pragma unroll
    for (int v4 = 0; v4 < 4; ++v4) {
      const int R = R0 + quad * 4 + v4;
#pragma unroll
      for (int j = 0; j < 6; ++j)
        o[R * NN + j * 16 + ln] = acc[j][v4];
    }
  }
}

extern "C" void kernel_launch(void* const* d_in, const int* in_sizes, int n_in,
                              void* d_out, int out_size, void* d_ws, size_t ws_size,
                              hipStream_t stream) {
  (void)in_sizes; (void)n_in; (void)out_size; (void)d_ws; (void)ws_size;
  hipFuncSetAttribute(reinterpret_cast<const void*>(doc_kernel),
                      hipFuncAttributeMaxDynamicSharedMemorySize, SMEM_BYTES);
  doc_kernel<<<GRID, NT, SMEM_BYTES, stream>>>(
      (const float*)d_in[0], (const float*)d_in[1], (const float*)d_in[2],
      (const float*)d_in[3], (const float*)d_in[4], (float*)d_out);
}

// Round 2
// 251.155 us; speedup vs baseline: 1.1856x; 1.1856x over previous
//
#include <hip/hip_runtime.h>

// DynamicOversizeConv2d: per (b,c) pair [2048 total], 96x96 matrices:
//   M_h = softmax_rows(Q K^T) + band_h(c);  M_w = softmax_rows(Q^T K) + band_w(c)
//   Out = (M_h V) M_w^T
// Inputs fp32, output fp32, internal compute fp16 MFMA (absmax 0.031 vs 0.119).
//
// R7: occupancy attack. R6 post-mortem: register prefetch spilled (VGPR cap 84,
// +26MB scratch writes) -> revert persistence. Bottleneck remains latency
// (all pipes <20%). LDS 80KB/pair caps 2 pairs/CU, so raise waves/pair:
// NT=768 (12 waves), 24 waves/CU (was 12).
//  - Phase 1: waves 0-5 do stage A (S_h rows, wave-local softmax, M_h->b0);
//    waves 6-11 concurrently do stage C (S_w rows, softmax, M_w held in acc
//    across B2, then banded into b1). Independent stages -> no extra sync.
//  - Phase 2: all 12 waves split stages B/D as (16-row stripe) x (48-col half);
//    no softmax there so no cross-wave reduction anywhere.
//  - Direct global stores from acc (fp32 ostage + 2 barriers removed).
// Barriers: 4 (was 5). VGPR budget 85 for 6 waves/SIMD -> __launch_bounds__(768,6).

typedef unsigned short u16;
typedef unsigned int u32;
typedef __attribute__((ext_vector_type(8))) _Float16 half8;
typedef __attribute__((ext_vector_type(4))) float floatx4;

#define NN 96
#define LD 104            // f16-tile row pitch (elems): 208 B = 16B-aligned rows
#define NT 768
#define PAIRS 2048
#define IMG 9216
#define SMEM_BYTES (4 * NN * LD * 2 + 26 * 4)  // 79,976 -> 2 blocks/CU (160K exactly)

__device__ __forceinline__ u16 f2h(float f) {
  union { _Float16 h; u16 u; } x;
  x.h = (_Float16)f;  // v_cvt_f16_f32 RNE
  return x.u;
}
__device__ __forceinline__ u32 pk(float lo, float hi) {
  return (u32)f2h(lo) | ((u32)f2h(hi) << 16);
}

// Workgroup barrier without __syncthreads' vmcnt(0) drain: LDS ordering via
// explicit lgkmcnt(0); memory clobbers pin LDS ops. Global loads/stores may
// stay in flight across it (register data only).
__device__ __forceinline__ void bar() {
  asm volatile("s_waitcnt lgkmcnt(0)" ::: "memory");
  __builtin_amdgcn_s_barrier();
  asm volatile("" ::: "memory");
}

// acc[j] = D[arow-stripe rows][(j0+j)*16+ln], A rows from A-tile, BT rows from
// B-tile. 3 k-steps of 32. NJ=6: full row; NJ=3: 48-col half.
template <int NJ>
__device__ __forceinline__ void mm(const u16* A, const u16* B, int arow, int ln,
                                   int quad, int j0, floatx4* acc) {
#pragma unroll
  for (int j = 0; j < NJ; ++j) acc[j] = (floatx4){0.f, 0.f, 0.f, 0.f};
#pragma unroll
  for (int ks = 0; ks < 3; ++ks) {
    const int kb = ks * 32 + quad * 8;
    const half8 a = *(const half8*)(A + arow * LD + kb);
    half8 b[NJ];
#pragma unroll
    for (int j = 0; j < NJ; ++j)
      b[j] = *(const half8*)(B + ((j0 + j) * 16 + ln) * LD + kb);
#pragma unroll
    for (int j = 0; j < NJ; ++j)
      acc[j] = __builtin_amdgcn_mfma_f32_16x16x32_f16(a, b[j], acc[j], 0, 0, 0);
  }
}

// Wave-local row softmax: row R = R0+quad*4+v lives in one quad across acc[0..5].
__device__ __forceinline__ void softmax_inplace(floatx4 acc[6]) {
#pragma unroll
  for (int v = 0; v < 4; ++v) {
    float m = acc[0][v];
#pragma unroll
    for (int j = 1; j < 6; ++j) m = fmaxf(m, acc[j][v]);
    m = fmaxf(m, __shfl_xor(m, 1));
    m = fmaxf(m, __shfl_xor(m, 2));
    m = fmaxf(m, __shfl_xor(m, 4));
    m = fmaxf(m, __shfl_xor(m, 8));
    float s = 0.f;
#pragma unroll
    for (int j = 0; j < 6; ++j) {
      const float e = __expf(acc[j][v] - m);
      acc[j][v] = e;
      s += e;
    }
    s += __shfl_xor(s, 1);
    s += __shfl_xor(s, 2);
    s += __shfl_xor(s, 4);
    s += __shfl_xor(s, 8);
    const float inv = __builtin_amdgcn_rcpf(s);
#pragma unroll
    for (int j = 0; j < 6; ++j) acc[j][v] *= inv;
  }
}

// Add band and store f16 stripe rows to D.
__device__ __forceinline__ void band_store(const floatx4 acc[6], int R0, int ln,
                                           int quad, const float* band13, u16* D) {
#pragma unroll
  for (int v = 0; v < 4; ++v) {
    const int R = R0 + quad * 4 + v;
#pragma unroll
    for (int j = 0; j < 6; ++j) {
      const int C = j * 16 + ln;
      const int off = C - R + 6;
      const float bnd = ((unsigned)off < 13u) ? band13[off] : 0.f;
      D[R * LD + C] = f2h(acc[j][v] + bnd);
    }
  }
}

extern "C" __global__ void __launch_bounds__(NT, 6)
doc_kernel(const float* __restrict__ qg, const float* __restrict__ kg,
           const float* __restrict__ vg, const float* __restrict__ khg,
           const float* __restrict__ kwg, float* __restrict__ og) {
  extern __shared__ char smem[];
  u16* b0 = (u16*)smem;       // Q   -> M_h
  u16* b1 = b0 + NN * LD;     // K   -> M_w
  u16* b2 = b1 + NN * LD;     // Q^T -> V^T
  u16* b3 = b2 + NN * LD;     // K^T -> V1
  float* kh13 = (float*)(b3 + NN * LD);
  float* kw13 = kh13 + 13;

  const int pair = blockIdx.x;
  const int c = pair & 255;
  const int tid = threadIdx.x;
  const int lane = tid & 63;
  const int wv = tid >> 6;      // 0..11
  const int quad = lane >> 4;
  const int ln = lane & 15;

  const float* q = qg + (size_t)pair * IMG;
  const float* k = kg + (size_t)pair * IMG;
  const float* v = vg + (size_t)pair * IMG;
  float* o = og + (size_t)pair * IMG;

  if (tid < 13)
    kh13[tid] = khg[c * 13 + tid];
  else if (tid < 26)
    kw13[tid - 13] = kwg[c * 13 + tid - 13];

  // Staging: 2304 tasks of (2 rows x 2 cols), 3/thread. m=t/192 (col super of
  // 8), rs=(t%192)/4 (row pair), g=t&3 (col-pair sub). Per wave: fixed m, 16
  // rs, 4 g -> 32B global granules; transposed store bank = (8g+rs)%32 -> 2-way.
  int r0_[3], c0_[3];
  u32 vh[3][2];
#pragma unroll
  for (int it = 0; it < 3; ++it) {
    const int t = tid + it * NT;
    const int m = t / 192;
    const int rs = (t % 192) >> 2;
    const int g = t & 3;
    const int r0 = rs * 2;
    const int c0 = m * 8 + g * 2;
    r0_[it] = r0;
    c0_[it] = c0;
    const int src = r0 * NN + c0;
    const float2 qa = *(const float2*)(q + src);
    const float2 qb = *(const float2*)(q + src + NN);
    const float2 ka = *(const float2*)(k + src);
    const float2 kb = *(const float2*)(k + src + NN);
    const float2 va = *(const float2*)(v + src);
    const float2 vb = *(const float2*)(v + src + NN);
    *(u32*)(b0 + r0 * LD + c0) = pk(qa.x, qa.y);
    *(u32*)(b0 + (r0 + 1) * LD + c0) = pk(qb.x, qb.y);
    *(u32*)(b1 + r0 * LD + c0) = pk(ka.x, ka.y);
    *(u32*)(b1 + (r0 + 1) * LD + c0) = pk(kb.x, kb.y);
    // transposed tiles: T[col][r0] = f16(row r0) | f16(row r0+1)<<16
    *(u32*)(b2 + (c0 + 0) * LD + r0) = pk(qa.x, qb.x);
    *(u32*)(b2 + (c0 + 1) * LD + r0) = pk(qa.y, qb.y);
    *(u32*)(b3 + (c0 + 0) * LD + r0) = pk(ka.x, kb.x);
    *(u32*)(b3 + (c0 + 1) * LD + r0) = pk(ka.y, kb.y);
    vh[it][0] = pk(va.x, vb.x);
    vh[it][1] = pk(va.y, vb.y);
  }
  bar();  // B1

  floatx4 acc[6];

  // Phase 1 (split waves): A-waves (0-5): S_h = Q K^T on own 16-row stripe,
  // softmax, +band_h -> M_h into b0 own stripe (only self reads it in stage B's
  // A-operand path via b0? -- read after B3 by stripe waves; barrier-covered).
  // C-waves (6-11): S_w = Q^T K on own stripe, softmax; M_w stays in acc until
  // b1 (K) is dead at B2.
  if (wv < 6) {
    mm<6>(b0, b1, wv * 16 + ln, ln, quad, 0, acc);
    softmax_inplace(acc);
    band_store(acc, wv * 16, ln, quad, kh13, b0);
  } else {
    mm<6>(b2, b3, (wv - 6) * 16 + ln, ln, quad, 0, acc);
    softmax_inplace(acc);
  }
  bar();  // B2: Q/K/QT/KT all dead

  if (wv >= 6) band_store(acc, (wv - 6) * 16, ln, quad, kw13, b1);  // M_w -> b1
#pragma unroll
  for (int it = 0; it < 3; ++it) {  // V^T -> b2 (over dead Q^T)
    *(u32*)(b2 + (c0_[it] + 0) * LD + r0_[it]) = vh[it][0];
    *(u32*)(b2 + (c0_[it] + 1) * LD + r0_[it]) = vh[it][1];
  }
  bar();  // B3: M_h, M_w, V^T visible

  // Phase 2 (all 12 waves): wave = (stripe s, col-half h).
  const int s = wv >> 1;
  const int h = wv & 1;
  const int arow = s * 16 + ln;
  floatx4 a2[3];

  // Stage B: V1[s-stripe][48h..+47] = M_h(b0) V (BT = V^T in b2); f16 -> b3.
  mm<3>(b0, b2, arow, ln, quad, 3 * h, a2);
#pragma unroll
  for (int v4 = 0; v4 < 4; ++v4) {
    const int R = s * 16 + quad * 4 + v4;
#pragma unroll
    for (int j = 0; j < 3; ++j)
      b3[R * LD + (3 * h + j) * 16 + ln] = f2h(a2[j][v4]);
  }
  bar();  // B4: V1 complete (stage D needs both col-halves of own stripe)

  // Stage D: Out[s-stripe][48h..+47] = V1(b3) M_w^T (BT = M_w in b1).
  // Direct global stores: per (j,v4) each quad writes 64B contiguous.
  mm<3>(b3, b1, arow, ln, quad, 3 * h, a2);
#pragma unroll
  for (int v4 = 0; v4 < 4; ++v4) {
    const int R = s * 16 + quad * 4 + v4;
#pragma unroll
    for (int j = 0; j < 3; ++j)
      o[R * NN + (3 * h + j) * 16 + ln] = a2[j][v4];
  }
}

extern "C" void kernel_launch(void* const* d_in, const int* in_sizes, int n_in,
                              void* d_out, int out_size, void* d_ws, size_t ws_size,
                              hipStream_t stream) {
  (void)in_sizes; (void)n_in; (void)out_size; (void)d_ws; (void)ws_size;
  hipFuncSetAttribute(reinterpret_cast<const void*>(doc_kernel),
                      hipFuncAttributeMaxDynamicSharedMemorySize, SMEM_BYTES);
  doc_kernel<<<PAIRS, NT, SMEM_BYTES, stream>>>(
      (const float*)d_in[0], (const float*)d_in[1], (const float*)d_in[2],
      (const float*)d_in[3], (const float*)d_in[4], (float*)d_out);
}